// Round 5
// baseline (209.964 us; speedup 1.0000x reference)
//
#include <hip/hip_runtime.h>
#include <stdint.h>

typedef unsigned short u16;
typedef unsigned int u32;
typedef __bf16 bf16_t;
typedef __bf16 bf16x4 __attribute__((ext_vector_type(4)));
typedef __bf16 bf16x8 __attribute__((ext_vector_type(8)));
typedef float f32x4 __attribute__((ext_vector_type(4)));
typedef float f32x16 __attribute__((ext_vector_type(16)));

#define LOG2E 1.4426950408889634f
#define MFMA32(a, b, c) __builtin_amdgcn_mfma_f32_32x32x16_bf16(a, b, c, 0, 0, 0)

__device__ __forceinline__ u16 f2bf(float f) {
    union { float f; unsigned int u; } v; v.f = f;
    unsigned int r = v.u + 0x7fffu + ((v.u >> 16) & 1u);
    return (u16)(r >> 16);
}

__device__ __forceinline__ bf16x8 ld8f_bf(const float* __restrict__ p) {
    float4 a = *reinterpret_cast<const float4*>(p);
    float4 b = *reinterpret_cast<const float4*>(p + 4);
    bf16x8 r;
    r[0] = (bf16_t)a.x; r[1] = (bf16_t)a.y; r[2] = (bf16_t)a.z; r[3] = (bf16_t)a.w;
    r[4] = (bf16_t)b.x; r[5] = (bf16_t)b.y; r[6] = (bf16_t)b.z; r[7] = (bf16_t)b.w;
    return r;
}

__device__ __forceinline__ u32 cvt_pk_bf16(float a, float b) {
    u32 r;
    asm("v_cvt_pk_bf16_f32 %0, %1, %2" : "=v"(r) : "v"(a), "v"(b));
    return r;
}

__device__ __forceinline__ void plane32_swap(u32& a, u32& b) {
    asm("v_permlane32_swap_b32 %0, %1" : "+v"(a), "+v"(b));
}

// Build PV B-operand fragment (16 keys) from 8 consecutive QK C-regs.
__device__ __forceinline__ bf16x8 pack8(const float* p) {
    u32 c0 = cvt_pk_bf16(p[0], p[1]);
    u32 c1 = cvt_pk_bf16(p[2], p[3]);
    u32 c2 = cvt_pk_bf16(p[4], p[5]);
    u32 c3 = cvt_pk_bf16(p[6], p[7]);
    plane32_swap(c0, c2);
    plane32_swap(c1, c3);
    union { u32 u[4]; bf16x8 v; } f;
    f.u[0] = c0; f.u[1] = c1; f.u[2] = c2; f.u[3] = c3;
    return f.v;
}

// async global->LDS, 16B per lane; LDS dest wave-uniform base + lane*16
__device__ __forceinline__ void g2lds16(const u16* g, u16* l) {
    __builtin_amdgcn_global_load_lds(
        (const __attribute__((address_space(1))) unsigned int*)g,
        (__attribute__((address_space(3))) unsigned int*)l, 16, 0, 0);
}

// ---------------------------------------------------------------------------
// Kernel 1: x[B,C,N] fp32 -> xT[B,N,C] bf16, PRE-SWIZZLED per 16B granule:
// row n, granule g stored at granule slot g^(n&7). Blocks >= 2048 convert
// weights to bf16: wqkb = [64 rows (Wq||Wk)][32 granules swizzled g^(n&7)],
// wvb = 8 slices x 1024 granules (slot d holds Wv[d>>2][slice*32+((d&3)^((d>>2)&3))*8..]).
// ---------------------------------------------------------------------------
__global__ __launch_bounds__(256) void k_transpose(
    const float* __restrict__ x,
    const float* __restrict__ Wq, const float* __restrict__ Wk,
    const float* __restrict__ Wv,
    u16* __restrict__ xT, u16* __restrict__ wqkb, u16* __restrict__ wvb) {
    int blk = blockIdx.x;
    int t = threadIdx.x;
    if (blk >= 2048) {
        if (blk == 2048) {          // Wq||Wk -> wqkb (2048 granules)
            for (int j = 0; j < 8; ++j) {
                int fg = j * 256 + t;
                int n = fg >> 5, g = fg & 31;
                const float* src = (n < 32) ? (Wq + (size_t)n * 256 + g * 8)
                                            : (Wk + (size_t)(n - 32) * 256 + g * 8);
                *reinterpret_cast<bf16x8*>(wqkb + n * 256 + ((g ^ (n & 7)) << 3)) =
                    ld8f_bf(src);
            }
        } else {                    // Wv -> wvb (8192 granules, blocks 2049..2052)
            int base = (blk - 2049) * 2048;
            for (int j = 0; j < 8; ++j) {
                int fg = base + j * 256 + t;
                int slice = fg >> 10, d = fg & 1023;
                int co = d >> 2, g2 = (d & 3) ^ (co & 3);
                *reinterpret_cast<bf16x8*>(wvb + fg * 8) =
                    ld8f_bf(Wv + (size_t)co * 256 + slice * 32 + g2 * 8);
            }
        }
        return;
    }
    __shared__ u16 tile[64][68];
    int b = blk >> 8;
    int r = blk & 255;
    int c0 = (r & 3) * 64;
    int n0 = (r >> 2) * 64;
    const float* xb = x + (size_t)b * 256 * 4096;
    u16* xTb = xT + (size_t)b * 4096 * 256;
    int lc = t >> 4;
    int l4 = (t & 15) * 4;
    #pragma unroll
    for (int p = 0; p < 4; ++p) {
        int c = lc + p * 16;
        float4 v = *reinterpret_cast<const float4*>(xb + (size_t)(c0 + c) * 4096 + n0 + l4);
        tile[c][l4 + 0] = f2bf(v.x); tile[c][l4 + 1] = f2bf(v.y);
        tile[c][l4 + 2] = f2bf(v.z); tile[c][l4 + 3] = f2bf(v.w);
    }
    __syncthreads();
    #pragma unroll
    for (int p = 0; p < 4; ++p) {
        int n = lc + p * 16;
        ushort4 v;
        v.x = tile[l4 + 0][n]; v.y = tile[l4 + 1][n];
        v.z = tile[l4 + 2][n]; v.w = tile[l4 + 3][n];
        int gslot = ((c0 + l4) >> 3) ^ ((n0 + n) & 7);
        *reinterpret_cast<ushort4*>(
            xTb + (size_t)(n0 + n) * 256 + (gslot << 3) + (l4 & 7)) = v;
    }
}

// ---------------------------------------------------------------------------
// Kernel 2 (v8): fused q/k/v projection. ONLY Xs (the 4-wave-shared x tile)
// lives in LDS. QK B-fragments (wqkb) and Wv A-fragments (wvb) load straight
// from global (L2-hot, staged layouts make the old LDS index exprs valid
// verbatim). ONE barrier total; the 8-step c-loop is barrier-free and fully
// unrolled so the compiler pipelines L2 loads under MFMAs.
// ---------------------------------------------------------------------------
__global__ __launch_bounds__(256, 2) void k_proj(
    const u16* __restrict__ xT, const u16* __restrict__ wqkb,
    const u16* __restrict__ wvb,
    const float* __restrict__ bq, const float* __restrict__ bk,
    const float* __restrict__ bv,
    u16* __restrict__ qt, u16* __restrict__ kt, u16* __restrict__ vt) {
    __shared__ u16 Xs[64 * 256];
    int blk = blockIdx.x;
    int b = blk & 7;
    int n0 = (blk >> 3) * 64;
    int t = threadIdx.x;
    int w = t >> 6;
    int lane = t & 63;
    int lo = lane & 15;
    int q = lane >> 4;
    const u16* xTb = xT + (size_t)b * 4096 * 256;

    // ---- stage Xs: linear async copy of pre-swizzled xT slab ----
    #pragma unroll
    for (int p = 0; p < 8; ++p)
        g2lds16(xTb + (size_t)n0 * 256 + (p * 256 + t) * 8, &Xs[(p * 256 + w * 64) * 8]);

    f32x4 accqk[4] = {};
    f32x4 accv[16];
    #pragma unroll
    for (int i = 0; i < 16; ++i) accv[i] = f32x4{0.f, 0.f, 0.f, 0.f};

    int rowA = w * 16 + lo;
    int cw = w * 64;
    __syncthreads();   // Xs staged (drains vmcnt)

    #pragma unroll
    for (int c0 = 0; c0 < 256; c0 += 32) {
        int K = c0 >> 3;
        bf16x8 a = *reinterpret_cast<const bf16x8*>(
            &Xs[(rowA * 32 + ((K + q) ^ (lo & 7))) * 8]);
        #pragma unroll
        for (int ot = 0; ot < 4; ++ot) {
            bf16x8 bb = *reinterpret_cast<const bf16x8*>(
                wqkb + ((ot * 16 + lo) * 32 + ((K + q) ^ (lo & 7))) * 8);
            accqk[ot] = __builtin_amdgcn_mfma_f32_16x16x32_bf16(a, bb, accqk[ot], 0, 0, 0);
        }
        bf16x8 xbf[4];
        #pragma unroll
        for (int nt = 0; nt < 4; ++nt)
            xbf[nt] = *reinterpret_cast<const bf16x8*>(
                &Xs[((nt * 16 + lo) * 32 + ((K + q) ^ (lo & 7))) * 8]);
        #pragma unroll
        for (int ct = 0; ct < 4; ++ct) {
            int co = cw + ct * 16 + lo;
            bf16x8 av = *reinterpret_cast<const bf16x8*>(
                wvb + (size_t)(c0 >> 5) * 8192 + (co * 4 + (q ^ (co & 3))) * 8);
            #pragma unroll
            for (int nt = 0; nt < 4; ++nt)
                accv[ct * 4 + nt] = __builtin_amdgcn_mfma_f32_16x16x32_bf16(
                    av, xbf[nt], accv[ct * 4 + nt], 0, 0, 0);
        }
    }
    #pragma unroll
    for (int ot = 0; ot < 4; ++ot) {
        float bias = (ot < 2) ? bq[ot * 16 + lo] : bk[(ot - 2) * 16 + lo];
        #pragma unroll
        for (int r = 0; r < 4; ++r) {
            int n = n0 + w * 16 + q * 4 + r;
            float val = accqk[ot][r] + bias;
            if (ot < 2) qt[((size_t)b * 4096 + n) * 32 + ot * 16 + lo] = f2bf(val * LOG2E);
            else        kt[((size_t)b * 4096 + n) * 32 + (ot - 2) * 16 + lo] = f2bf(val);
        }
    }
    #pragma unroll
    for (int ct = 0; ct < 4; ++ct) {
        #pragma unroll
        for (int nt = 0; nt < 4; ++nt) {
            int nt_g = (n0 >> 4) + nt;
            #pragma unroll
            for (int r = 0; r < 4; ++r) {
                int co = cw + ct * 16 + q * 4 + r;
                float val = accv[ct * 4 + nt][r] + bv[co];
                vt[(((size_t)b * 256 + nt_g) * 256 + co) * 16 + lo] = f2bf(val);
            }
        }
    }
}

// ---------------------------------------------------------------------------
// Kernel 3 (v8): v7 pipelined flash + (a) s_setprio around PV MFMA clusters
// (T5), (b) row-sum via ones-MFMA into a spare accumulator (Lacc) instead of
// 32 VALU adds + shuffle per step.
// ---------------------------------------------------------------------------
#define FLASH_PV_HALF1(FC0, FC1, Vc_)                                          \
    {                                                                          \
        bf16x8 v0_ = *reinterpret_cast<const bf16x8*>(Vc_ + gslot8);           \
        bf16x8 v1_ = *reinterpret_cast<const bf16x8*>(Vc_ + 512 + gslot8);     \
        bf16x8 v2_ = *reinterpret_cast<const bf16x8*>(Vc_ + 1024 + gslot8);    \
        bf16x8 v3_ = *reinterpret_cast<const bf16x8*>(Vc_ + 1536 + gslot8);    \
        __builtin_amdgcn_s_setprio(1);                                         \
        O0 = MFMA32(v0_, FC0, O0); O1 = MFMA32(v1_, FC0, O1);                  \
        O2 = MFMA32(v2_, FC0, O2); O3 = MFMA32(v3_, FC0, O3);                  \
        __builtin_amdgcn_s_setprio(0);                                         \
        bf16x8 v4_ = *reinterpret_cast<const bf16x8*>(Vc_ + 2048 + gslot8);    \
        bf16x8 v5_ = *reinterpret_cast<const bf16x8*>(Vc_ + 2560 + gslot8);    \
        bf16x8 v6_ = *reinterpret_cast<const bf16x8*>(Vc_ + 3072 + gslot8);    \
        bf16x8 v7_ = *reinterpret_cast<const bf16x8*>(Vc_ + 3584 + gslot8);    \
        __builtin_amdgcn_s_setprio(1);                                         \
        O0 = MFMA32(v4_, FC1, O0); O1 = MFMA32(v5_, FC1, O1);                  \
        O2 = MFMA32(v6_, FC1, O2); O3 = MFMA32(v7_, FC1, O3);                  \
        __builtin_amdgcn_s_setprio(0);                                         \
    }

#define FLASH_PV_HALF2(FC2, FC3, Vc_)                                          \
    {                                                                          \
        bf16x8 v0_ = *reinterpret_cast<const bf16x8*>(Vc_ + 4096 + gslot8);    \
        bf16x8 v1_ = *reinterpret_cast<const bf16x8*>(Vc_ + 4608 + gslot8);    \
        bf16x8 v2_ = *reinterpret_cast<const bf16x8*>(Vc_ + 5120 + gslot8);    \
        bf16x8 v3_ = *reinterpret_cast<const bf16x8*>(Vc_ + 5632 + gslot8);    \
        __builtin_amdgcn_s_setprio(1);                                         \
        O0 = MFMA32(v0_, FC2, O0); O1 = MFMA32(v1_, FC2, O1);                  \
        O2 = MFMA32(v2_, FC2, O2); O3 = MFMA32(v3_, FC2, O3);                  \
        __builtin_amdgcn_s_setprio(0);                                         \
        bf16x8 v4_ = *reinterpret_cast<const bf16x8*>(Vc_ + 6144 + gslot8);    \
        bf16x8 v5_ = *reinterpret_cast<const bf16x8*>(Vc_ + 6656 + gslot8);    \
        bf16x8 v6_ = *reinterpret_cast<const bf16x8*>(Vc_ + 7168 + gslot8);    \
        bf16x8 v7_ = *reinterpret_cast<const bf16x8*>(Vc_ + 7680 + gslot8);    \
        __builtin_amdgcn_s_setprio(1);                                         \
        O0 = MFMA32(v4_, FC3, O0); O1 = MFMA32(v5_, FC3, O1);                  \
        O2 = MFMA32(v6_, FC3, O2); O3 = MFMA32(v7_, FC3, O3);                  \
        __builtin_amdgcn_s_setprio(0);                                         \
    }

#define FLASH_ITER(S_, KC0, KC1, KC2, KC3, KN0, KN1, KN2, KN3,                 \
                   FC0, FC1, FC2, FC3, FN0, FN1, FN2, FN3, VDN)                \
    {                                                                          \
        const int s_ = (S_);                                                   \
        const u16* kp_ = kbase + (size_t)(((s_ + 2) & 63) * 2048);             \
        KN0 = *reinterpret_cast<const bf16x8*>(kp_);                           \
        KN1 = *reinterpret_cast<const bf16x8*>(kp_ + 16);                      \
        KN2 = *reinterpret_cast<const bf16x8*>(kp_ + 1024);                    \
        KN3 = *reinterpret_cast<const bf16x8*>(kp_ + 1040);                    \
        const u16* vs_ = vstage + (size_t)(s_ + 1) * 16384;                    \
        g2lds16(vs_,        VDN);                                              \
        g2lds16(vs_ + 512,  VDN + 512);                                        \
        g2lds16(vs_ + 1024, VDN + 1024);                                       \
        g2lds16(vs_ + 1536, VDN + 1536);                                       \
        f32x16 S0_ = MFMA32(KC0, qf0, z16); S0_ = MFMA32(KC1, qf1, S0_);       \
        f32x16 S1_ = MFMA32(KC2, qf0, z16); S1_ = MFMA32(KC3, qf1, S1_);       \
        const u16* Vc_ = Vs[s_ & 1];                                           \
        float p0_[16];                                                         \
        _Pragma("unroll")                                                      \
        for (int i_ = 0; i_ < 16; ++i_) p0_[i_] = __builtin_amdgcn_exp2f(S0_[i_]); \
        FN0 = pack8(p0_); FN1 = pack8(p0_ + 8);                                \
        Lacc = MFMA32(ones, FN0, Lacc); Lacc = MFMA32(ones, FN1, Lacc);        \
        FLASH_PV_HALF1(FC0, FC1, Vc_)                                          \
        float p1_[16];                                                         \
        _Pragma("unroll")                                                      \
        for (int i_ = 0; i_ < 16; ++i_) p1_[i_] = __builtin_amdgcn_exp2f(S1_[i_]); \
        FN2 = pack8(p1_); FN3 = pack8(p1_ + 8);                                \
        Lacc = MFMA32(ones, FN2, Lacc); Lacc = MFMA32(ones, FN3, Lacc);        \
        FLASH_PV_HALF2(FC2, FC3, Vc_)                                          \
        __syncthreads();                                                       \
    }

__global__ __launch_bounds__(256, 2) void k_flash(
    const u16* __restrict__ qt, const u16* __restrict__ kt,
    const u16* __restrict__ vt, const float* __restrict__ x,
    const float* __restrict__ gamma, float* __restrict__ out) {
    __shared__ u16 Vs[2][8192];   // 16 chunks (kc*4+cg) x 512 u16 per buffer
    int blk = blockIdx.x;
    int b = blk & 7;
    int rest = blk >> 3;
    int m0 = (rest & 31) * 128;
    int ch0 = (rest >> 5) * 128;
    int t = threadIdx.x;
    int w = t >> 6;
    int lane = t & 63;
    int la = lane & 31;
    int hi = lane >> 5;

    const u16* qtb = qt + (size_t)b * 4096 * 32;
    const u16* ktb = kt + (size_t)b * 4096 * 32;
    const u16* vtb = vt + (size_t)b * 256 * 256 * 16;

    int qw0 = m0 + w * 32;
    bf16x8 qf0 = *reinterpret_cast<const bf16x8*>(qtb + (size_t)(qw0 + la) * 32 + hi * 8);
    bf16x8 qf1 = *reinterpret_cast<const bf16x8*>(qtb + (size_t)(qw0 + la) * 32 + 16 + hi * 8);

    const u16* kbase = ktb + (size_t)la * 32 + hi * 8;

    int g = la * 2 + hi;
    int gslot8 = (g ^ (g >> 3)) * 8;   // read-slot swizzle (involution)
    int sg = lane ^ (lane >> 3);       // pre-swizzled staging source granule
    const u16* vstage = vtb + ((size_t)(w * 256) + ch0) * 16 + sg * 8;
    u16* vd0 = &Vs[0][w * 2048];
    u16* vd1 = &Vs[1][w * 2048];

    f32x16 O0 = {}, O1 = {}, O2 = {}, O3 = {};
    f32x16 Lacc = {};
    const f32x16 z16 = {};
    bf16x8 ones;
    #pragma unroll
    for (int i = 0; i < 8; ++i) ones[i] = (bf16_t)1.0f;

    bf16x8 kA0, kA1, kA2, kA3, kB0, kB1, kB2, kB3;
    bf16x8 fA0, fA1, fA2, fA3, fB0, fB1, fB2, fB3;

    // ---- prologue: K(0)->kA, stage V(0), K(1)->kB, frags(0)->fA ----
    kA0 = *reinterpret_cast<const bf16x8*>(kbase);
    kA1 = *reinterpret_cast<const bf16x8*>(kbase + 16);
    kA2 = *reinterpret_cast<const bf16x8*>(kbase + 1024);
    kA3 = *reinterpret_cast<const bf16x8*>(kbase + 1040);
    g2lds16(vstage,        vd0);
    g2lds16(vstage + 512,  vd0 + 512);
    g2lds16(vstage + 1024, vd0 + 1024);
    g2lds16(vstage + 1536, vd0 + 1536);
    kB0 = *reinterpret_cast<const bf16x8*>(kbase + 2048);
    kB1 = *reinterpret_cast<const bf16x8*>(kbase + 2064);
    kB2 = *reinterpret_cast<const bf16x8*>(kbase + 3072);
    kB3 = *reinterpret_cast<const bf16x8*>(kbase + 3088);
    {
        f32x16 S0 = MFMA32(kA0, qf0, z16); S0 = MFMA32(kA1, qf1, S0);
        f32x16 S1 = MFMA32(kA2, qf0, z16); S1 = MFMA32(kA3, qf1, S1);
        float p0[16], p1[16];
        #pragma unroll
        for (int i = 0; i < 16; ++i) p0[i] = __builtin_amdgcn_exp2f(S0[i]);
        fA0 = pack8(p0); fA1 = pack8(p0 + 8);
        #pragma unroll
        for (int i = 0; i < 16; ++i) p1[i] = __builtin_amdgcn_exp2f(S1[i]);
        fA2 = pack8(p1); fA3 = pack8(p1 + 8);
        Lacc = MFMA32(ones, fA0, Lacc); Lacc = MFMA32(ones, fA1, Lacc);
        Lacc = MFMA32(ones, fA2, Lacc); Lacc = MFMA32(ones, fA3, Lacc);
    }
    __syncthreads();   // V(0) staged

    // ---- main loop: s = 0..61 (31 unrolled pairs) ----
    for (int ss = 0; ss < 31; ++ss) {
        int s0 = ss * 2;
        FLASH_ITER(s0,     kB0, kB1, kB2, kB3, kA0, kA1, kA2, kA3,
                           fA0, fA1, fA2, fA3, fB0, fB1, fB2, fB3, vd1)
        FLASH_ITER(s0 + 1, kA0, kA1, kA2, kA3, kB0, kB1, kB2, kB3,
                           fB0, fB1, fB2, fB3, fA0, fA1, fA2, fA3, vd0)
    }
    // ---- s = 62: full iter (produces frags(63), stages V(63)) ----
    FLASH_ITER(62, kB0, kB1, kB2, kB3, kA0, kA1, kA2, kA3,
                   fA0, fA1, fA2, fA3, fB0, fB1, fB2, fB3, vd1)
    // ---- s = 63: PV only ----
    {
        const u16* Vc_ = Vs[1];
        FLASH_PV_HALF1(fB0, fB1, Vc_)
        FLASH_PV_HALF2(fB2, fB3, Vc_)
    }

    // Lacc rows are all identical (ones x P): Lacc[0] = full row-sum for q=la
    float linv = 1.0f / Lacc[0];
    float gm = gamma[0];
    const float* xb = x + (size_t)b * 256 * 4096;
    float* ob = out + (size_t)b * 256 * 4096;
    int m = m0 + w * 32 + la;
    #pragma unroll
    for (int r = 0; r < 16; ++r) {
        int crow = (r & 3) + 8 * (r >> 2) + 4 * hi;
        size_t i0 = (size_t)(ch0 + crow) * 4096 + m;
        ob[i0]             = gm * (O0[r] * linv) + xb[i0];
        ob[i0 + 32 * 4096] = gm * (O1[r] * linv) + xb[i0 + 32 * 4096];
        ob[i0 + 64 * 4096] = gm * (O2[r] * linv) + xb[i0 + 64 * 4096];
        ob[i0 + 96 * 4096] = gm * (O3[r] * linv) + xb[i0 + 96 * 4096];
    }
}

// ---------------------------------------------------------------------------
// fp32 I/O. Internal bf16. Workspace: qt 2 + kt 2 + vt 16 = 20 MiB.
// d_out (32 MiB): xT bf16 16 MiB + wqkb 32 KiB + wvb 128 KiB (dead before
// k_flash writes out).
// ---------------------------------------------------------------------------
extern "C" void kernel_launch(void* const* d_in, const int* in_sizes, int n_in,
                              void* d_out, int out_size, void* d_ws, size_t ws_size,
                              hipStream_t stream) {
    const float* x     = (const float*)d_in[0];
    const float* Wq    = (const float*)d_in[1];
    const float* bq    = (const float*)d_in[2];
    const float* Wk    = (const float*)d_in[3];
    const float* bk    = (const float*)d_in[4];
    const float* Wv    = (const float*)d_in[5];
    const float* bv    = (const float*)d_in[6];
    const float* gamma = (const float*)d_in[7];
    float* out = (float*)d_out;

    char* ws = (char*)d_ws;
    u16* xT   = (u16*)d_out;                      // 16 MiB bf16 scratch in d_out
    u16* wqkb = (u16*)d_out + 8388608;            // 32 KiB
    u16* wvb  = (u16*)d_out + 8388608 + 16384;    // 128 KiB
    u16* qt = (u16*)ws;                           //  2 MiB [B,N,32]
    u16* kt = (u16*)(ws + 2097152);               //  2 MiB [B,N,32]
    u16* vt = (u16*)(ws + 2 * 2097152);           // 16 MiB [B,nt,ch,16]

    k_transpose<<<2053, 256, 0, stream>>>(x, Wq, Wk, Wv, xT, wqkb, wvb);
    k_proj<<<512, 256, 0, stream>>>(xT, wqkb, wvb, bq, bk, bv, qt, kt, vt);
    k_flash<<<512, 256, 0, stream>>>(qt, kt, vt, x, gamma, out);
}